// Round 4
// baseline (4556.723 us; speedup 1.0000x reference)
//
#include <hip/hip_runtime.h>
#include <hip/hip_cooperative_groups.h>

namespace cg = cooperative_groups;

#define NG 256
#define PI2F 6.28318530717958647692f
// padded LDS complex index: pad 1 float2 per 16 to break bank aliasing
#define PIDX(i) ((i) + ((i) >> 4))
#define HT_CELL 36
#define S1_POOL 50704

__device__ __forceinline__ float2 f2add(float2 a, float2 b){ return make_float2(a.x+b.x, a.y+b.y); }
__device__ __forceinline__ float2 f2sub(float2 a, float2 b){ return make_float2(a.x-b.x, a.y-b.y); }
__device__ __forceinline__ float2 cmul(float2 a, float2 b){ return make_float2(a.x*b.x - a.y*b.y, a.x*b.y + a.y*b.x); }

// ---------------------------------------------------------------------------
// 256-pt radix-4 Stockham FFT, 64 threads per FFT unit (u = lane 0..63).
// Buffers a,b are PIDX-padded (272 float2). tw[j]=exp(-2πi j/256).
// Result ends back in `a`. Caller must __syncthreads() after filling a/tw.
// (validated rounds 2-3)
// ---------------------------------------------------------------------------
template<bool INV>
__device__ __forceinline__ void fft256_r4(float2* a, float2* b, const float2* tw, int u)
{
#pragma unroll
    for (int st = 0; st < 4; ++st) {
        const int sl = 2 * st;
        const int q  = u & ((1 << sl) - 1);
        const int j1 = u - q;                 // p << sl  (twiddle index, <64)
        const float2 x0 = a[PIDX(u)];
        const float2 x1 = a[PIDX(u + 64)];
        const float2 x2 = a[PIDX(u + 128)];
        const float2 x3 = a[PIDX(u + 192)];
        float2 w1 = tw[j1];
        if (INV) w1.y = -w1.y;
        const float2 w2 = cmul(w1, w1);
        const float2 w3 = cmul(w1, w2);
        const float2 apc = f2add(x0, x2), amc = f2sub(x0, x2);
        const float2 bpd = f2add(x1, x3), bmd = f2sub(x1, x3);
        const float2 jb  = make_float2(-bmd.y, bmd.x);      // j*(b-d)
        const float2 t0  = f2add(apc, bpd);
        const float2 t2  = f2sub(apc, bpd);
        const float2 t1  = INV ? f2add(amc, jb) : f2sub(amc, jb);
        const float2 t3  = INV ? f2sub(amc, jb) : f2add(amc, jb);
        const int wb = q + (j1 << 2);         // q + 4*s*p
        const int ss = 1 << sl;
        b[PIDX(wb)]          = t0;
        b[PIDX(wb + ss)]     = cmul(w1, t1);
        b[PIDX(wb + 2 * ss)] = cmul(w2, t2);
        b[PIDX(wb + 3 * ss)] = cmul(w3, t3);
        __syncthreads();
        float2* tmp = a; a = b; b = tmp;
    }
}

__device__ __forceinline__ void init_tw(float2* tw, int tid)
{
    float s, c;
    __sincosf(-PI2F * (float)tid * (1.f / 256.f), &s, &c);
    tw[tid] = make_float2(c, s);
}

// ---------------------------------------------------------------------------
// conv unit: Q = Q0 + 0.01*conv2(relu(conv1(z))), 16x16 tile (validated r2/r3)
// ---------------------------------------------------------------------------
__device__ __forceinline__ void conv_unit(char* pool,
    const float* __restrict__ zsrc, const float* __restrict__ Q0,
    const float* __restrict__ W1, const float* __restrict__ b1,
    const float* __restrict__ W2, const float* __restrict__ b2,
    float* __restrict__ Qout, int bid)
{
    float*  zt  = (float*)pool;                       // 1600
    float*  ht  = (float*)(pool + 1600);              // 46656
    float4* w1s = (float4*)(pool + 48256);            // 1152
    float4* w2s = (float4*)(pool + 49408);            // 1152
    float*  b1s = (float*)(pool + 50560);             // 128
    float*  b2s = (float*)(pool + 50688);             // 4
    const int tid = threadIdx.x;
    const int b   = bid >> 8;
    const int ty0 = ((bid >> 4) & 15) * 16, tx0 = (bid & 15) * 16;

    if (tid < 72) {
        w1s[tid] = ((const float4*)W1)[tid];
        w2s[tid] = ((const float4*)W2)[tid];
    }
    if (tid < 32) b1s[tid] = b1[tid];
    if (tid == 0) b2s[0] = b2[0];

    for (int i = tid; i < 400; i += 256) {
        const int ly = i / 20, lx = i - ly * 20;
        const int gy = ty0 + ly - 2, gx = tx0 + lx - 2;
        float v = 0.f;
        if ((unsigned)gy < 256u && (unsigned)gx < 256u)
            v = zsrc[(b * NG + gy) * NG + gx];
        zt[ly * 20 + lx] = v;
    }
    __syncthreads();

    for (int i = tid; i < 324 * 8; i += 256) {
        const int pos = i >> 3, cg = i & 7;
        const int hy = pos / 18, hx = pos - hy * 18;
        const int gy = ty0 + hy - 1, gx = tx0 + hx - 1;
        float4 acc = make_float4(0.f, 0.f, 0.f, 0.f);
        if ((unsigned)gy < 256u && (unsigned)gx < 256u) {
            acc = make_float4(b1s[cg * 4], b1s[cg * 4 + 1],
                              b1s[cg * 4 + 2], b1s[cg * 4 + 3]);
#pragma unroll
            for (int dy = 0; dy < 3; dy++)
#pragma unroll
                for (int dx = 0; dx < 3; dx++) {
                    const float zv = zt[(hy + dy) * 20 + hx + dx];
                    const float4 w = w1s[(dy * 3 + dx) * 8 + cg];
                    acc.x += w.x * zv; acc.y += w.y * zv;
                    acc.z += w.z * zv; acc.w += w.w * zv;
                }
            acc.x = fmaxf(acc.x, 0.f); acc.y = fmaxf(acc.y, 0.f);
            acc.z = fmaxf(acc.z, 0.f); acc.w = fmaxf(acc.w, 0.f);
        }
        *((float4*)&ht[pos * HT_CELL + cg * 4]) = acc;
    }
    __syncthreads();

    const int oy = tid >> 4, ox = tid & 15;
    float qv = b2s[0];
#pragma unroll
    for (int dy = 0; dy < 3; dy++)
#pragma unroll
        for (int dx = 0; dx < 3; dx++) {
            const float* hcell = &ht[((oy + dy) * 18 + (ox + dx)) * HT_CELL];
#pragma unroll
            for (int cg = 0; cg < 8; cg++) {
                const float4 hv = *((const float4*)&hcell[cg * 4]);
                const float4 w  = w2s[(dy * 3 + dx) * 8 + cg];
                qv += w.x * hv.x + w.y * hv.y + w.z * hv.z + w.w * hv.w;
            }
        }
    const int gy = ty0 + oy, gx = tx0 + ox;
    Qout[(b * NG + gy) * NG + gx] = Q0[gy * NG + gx] + 0.01f * qv;
}

// ---------------------------------------------------------------------------
// fftA unit: 8 rows as 4 row-packed complex FFTs + Hermitian unpack,
// transposed write At[b][kx][y] in 64B lane chunks (validated r3)
// ---------------------------------------------------------------------------
__device__ __forceinline__ void fftA_unit(char* pool,
    const float* __restrict__ zsrc, float2* __restrict__ At, int g)
{
    float2* bufs = (float2*)pool;          // A_j = j*272, B_j = (4+j)*272
    float2* tw   = bufs + 2176;
    const int tid = threadIdx.x;
    const int b  = g >> 5;
    const int rg = g & 31;                 // row group of 8
    const int j  = tid >> 6, u = tid & 63;
    float2* A = bufs + j * 272;
    float2* B = bufs + (4 + j) * 272;

    init_tw(tw, tid);
    const int ya = rg * 8 + 2 * j;
    const float* r0 = zsrc + (b * NG + ya) * NG;
    const float* r1 = r0 + NG;
#pragma unroll
    for (int r = 0; r < 4; ++r) {
        const int x = u + 64 * r;
        A[PIDX(x)] = make_float2(r0[x], r1[x]);
    }
    __syncthreads();
    fft256_r4<false>(A, B, tw, u);

    const int k  = tid;
    const int km = (256 - k) & 255;
    float2 outv[8];
#pragma unroll
    for (int jj = 0; jj < 4; ++jj) {
        const float2* Aj = bufs + jj * 272;
        const float2 Zk = Aj[PIDX(k)], Zm = Aj[PIDX(km)];
        outv[2 * jj] = make_float2(0.5f * (Zk.x + Zm.x), 0.5f * (Zk.y - Zm.y));
        const float dx = Zk.x - Zm.x, dy = Zk.y + Zm.y;
        outv[2 * jj + 1] = make_float2(0.5f * dy, -0.5f * dx);
    }
    float4* dst = (float4*)(At + ((size_t)(b * NG + k)) * NG + rg * 8);
#pragma unroll
    for (int q4 = 0; q4 < 4; ++q4) dst[q4] = ((float4*)outv)[q4];
}

// ---------------------------------------------------------------------------
// BC unit: 4 kx-lines: fwd FFT along y, spectral multiplies (Hermitian-
// projection Nyquist masks), two packed inverse FFTs, writes Ct[f][b][y][kx]
// scaled by 1/256 (validated r2/r3)
// ---------------------------------------------------------------------------
__device__ __forceinline__ void bc_unit(char* pool,
    const float2* __restrict__ At, float2* __restrict__ Ct0,
    float2* __restrict__ Ct1, int unit)
{
    float2* bufs = (float2*)pool;   // A_j=j*272, B_j=(4+j)*272, C_j=(8+j)*272
    float2* tw   = bufs + 3264;
    const int b  = unit >> 6;
    const int kg = unit & 63;
    const int tid = threadIdx.x;
    const int j = tid >> 6, u = tid & 63;
    float2* A = bufs + j * 272;
    float2* B = bufs + (4 + j) * 272;
    float2* C = bufs + (8 + j) * 272;

    init_tw(tw, tid);
    const int kxl = 4 * kg + j;
    const float2* src = At + ((size_t)(b * NG + kxl)) * NG;
#pragma unroll
    for (int r = 0; r < 4; ++r) {
        const int x = u + 64 * r;
        A[PIDX(x)] = src[x];
    }
    __syncthreads();
    fft256_r4<false>(A, B, tw, u);

    const float kxv = (kxl < 128) ? (float)kxl : (float)(kxl - 256);
    const float kxm = (kxl == 128) ? 0.f : kxv;
#pragma unroll
    for (int r = 0; r < 4; ++r) {
        const int ky = u + 64 * r;
        const float kyv = (ky < 128) ? (float)ky : (float)(ky - 256);
        const float kym = (ky == 128) ? 0.f : kyv;
        const float K2 = kxv * kxv + kyv * kyv;
        const float il = (K2 > 0.f) ? (-1.f / K2) : 0.f;
        const float2 Z = A[PIDX(ky)];
        const float ar = -kxm * il, ai = -kym * il;
        A[PIDX(ky)] = make_float2(ar * Z.x - ai * Z.y, ar * Z.y + ai * Z.x);
        C[PIDX(ky)] = make_float2(-kym * Z.x - kxm * Z.y, -kym * Z.y + kxm * Z.x);
    }
    __syncthreads();

    fft256_r4<true>(A, B, tw, u);
    {   // field0 (u + i v), thread tid = y
        const int y = tid;
        const float sc = 1.f / 256.f;
        float2 ov[4];
#pragma unroll
        for (int jj = 0; jj < 4; ++jj) {
            const float2 r0 = (bufs + jj * 272)[PIDX(y)];
            ov[jj] = make_float2(r0.x * sc, r0.y * sc);
        }
        float4* dst = (float4*)(Ct0 + ((size_t)(b * NG + y)) * NG + 4 * kg);
        dst[0] = ((float4*)ov)[0];
        dst[1] = ((float4*)ov)[1];
    }
    fft256_r4<true>(C, B, tw, u);
    {   // field1 (zx + i zy)
        const int y = tid;
        const float sc = 1.f / 256.f;
        float2 ov[4];
#pragma unroll
        for (int jj = 0; jj < 4; ++jj) {
            const float2 r1 = (bufs + (8 + jj) * 272)[PIDX(y)];
            ov[jj] = make_float2(r1.x * sc, r1.y * sc);
        }
        float4* dst = (float4*)(Ct1 + ((size_t)(b * NG + y)) * NG + 4 * kg);
        dst[0] = ((float4*)ov)[0];
        dst[1] = ((float4*)ov)[1];
    }
}

// ---------------------------------------------------------------------------
// D unit: 2 (y,b)-lines, 4 inverse FFTs, fused time-step update (validated r3)
// ---------------------------------------------------------------------------
__device__ __forceinline__ void d_unit(char* pool,
    const float2* __restrict__ Ct0, const float2* __restrict__ Ct1,
    const float* __restrict__ zsrc, const float* __restrict__ Qb,
    float* __restrict__ zdst, float* __restrict__ outp, int unit)
{
    float2* bufs = (float2*)pool;   // A_j = j*272, B_j = (4+j)*272
    float2* tw   = bufs + 2176;
    const int b  = unit >> 7;
    const int yg = unit & 127;
    const int y0 = 2 * yg;
    const int tid = threadIdx.x;
    const int j = tid >> 6, u = tid & 63;
    float2* A = bufs + j * 272;
    float2* B = bufs + (4 + j) * 272;

    init_tw(tw, tid);
    const int   yl  = y0 + (j >> 1);
    const float2* src = ((j & 1) ? Ct1 : Ct0) + ((size_t)(b * NG + yl)) * NG;
#pragma unroll
    for (int r = 0; r < 4; ++r) {
        const int x = u + 64 * r;
        A[PIDX(x)] = src[x];
    }
    __syncthreads();
    fft256_r4<true>(A, B, tw, u);

    const float sc = 1.f / 256.f;
#pragma unroll
    for (int i0 = 0; i0 < 2; ++i0) {
        const int i  = tid + 256 * i0;
        const int ln = i >> 8, x = i & 255;
        const float2 uvv = (bufs + (2 * ln) * 272)[PIDX(x)];
        const float2 gzz = (bufs + (2 * ln + 1) * 272)[PIDX(x)];
        const float uu = uvv.x * sc, vv = uvv.y * sc;
        const float zx = gzz.x * sc, zy = gzz.y * sc;
        const int idx = (b * NG + y0 + ln) * NG + x;
        const float z0 = zsrc[idx];
        const float qv = Qb[idx];
        const float adv = uu * zx + vv * zy;
        const float zn = z0 + 0.01f * (-adv - 0.5f * vv - 0.05f * z0 + qv);
        zdst[idx] = zn;
        if (outp) outp[b * (4 * NG * NG) + (y0 + ln) * NG + x] = zn;
    }
}

// ---------------------------------------------------------------------------
// Cooperative mega-kernel: all 16 steps, grid.sync() at phase boundaries.
// Grid must be <= co-resident capacity (768 blocks = 3/CU, LDS-limited).
// ---------------------------------------------------------------------------
__global__ void __launch_bounds__(256, 3)
mega_kernel(const float* __restrict__ zeta, const float* __restrict__ Q0,
            const float* __restrict__ W1, const float* __restrict__ b1,
            const float* __restrict__ W2, const float* __restrict__ b2,
            float* __restrict__ outp, float* __restrict__ zbuf,
            float* __restrict__ Qb, float2* __restrict__ At,
            float2* __restrict__ Ct0, float2* __restrict__ Ct1)
{
    cg::grid_group grid = cg::this_grid();
    __shared__ __align__(16) char pool[S1_POOL];
    const int nb = gridDim.x;

    for (int step = 0; step < 16; ++step) {
        const float* zs = (step == 0) ? zeta : zbuf;
        for (int uu = blockIdx.x; uu < 2304; uu += nb) {
            __syncthreads();
            if (uu < 2048) conv_unit(pool, zs, Q0, W1, b1, W2, b2, Qb, uu);
            else           fftA_unit(pool, zs, At, uu - 2048);
        }
        grid.sync();
        for (int uu = blockIdx.x; uu < 512; uu += nb) {
            __syncthreads();
            bc_unit(pool, At, Ct0, Ct1, uu);
        }
        grid.sync();
        float* op = ((step & 3) == 3) ? (outp + (size_t)(step >> 2) * NG * NG)
                                      : nullptr;
        for (int uu = blockIdx.x; uu < 1024; uu += nb) {
            __syncthreads();
            d_unit(pool, Ct0, Ct1, zs, Qb, zbuf, op, uu);
        }
        grid.sync();
    }
}

// ---------------------------------------------------------------------------
// Fallback kernels (round-3 structure) in case cooperative launch fails.
// ---------------------------------------------------------------------------
__global__ void __launch_bounds__(256)
step1_kernel(const float* __restrict__ zsrc, const float* __restrict__ Q0,
             const float* __restrict__ W1, const float* __restrict__ b1,
             const float* __restrict__ W2, const float* __restrict__ b2,
             float* __restrict__ Qout, float2* __restrict__ At)
{
    __shared__ __align__(16) char pool[S1_POOL];
    if (blockIdx.x < 2048) conv_unit(pool, zsrc, Q0, W1, b1, W2, b2, Qout, blockIdx.x);
    else                   fftA_unit(pool, zsrc, At, blockIdx.x - 2048);
}

__global__ void __launch_bounds__(256)
fftBC_kernel(const float2* __restrict__ At, float2* __restrict__ Ct0,
             float2* __restrict__ Ct1)
{
    __shared__ __align__(16) char pool[28160];
    bc_unit(pool, At, Ct0, Ct1, blockIdx.x);
}

__global__ void __launch_bounds__(256)
fftD_kernel(const float2* __restrict__ Ct0, const float2* __restrict__ Ct1,
            const float* __restrict__ zsrc, const float* __restrict__ Qb,
            float* __restrict__ zdst, float* __restrict__ outp)
{
    __shared__ __align__(16) char pool[19456];
    d_unit(pool, Ct0, Ct1, zsrc, Qb, zdst, outp, blockIdx.x);
}

// ---------------------------------------------------------------------------
extern "C" void kernel_launch(void* const* d_in, const int* in_sizes, int n_in,
                              void* d_out, int out_size, void* d_ws, size_t ws_size,
                              hipStream_t stream)
{
    const float* zeta = (const float*)d_in[0];   // (8,256,256)
    const float* Q0   = (const float*)d_in[1];   // (256,256)
    const float* W1   = (const float*)d_in[2];   // (3,3,1,32)
    const float* b1   = (const float*)d_in[3];   // (32,)
    const float* W2   = (const float*)d_in[4];   // (3,3,32,1)
    const float* b2   = (const float*)d_in[5];   // (1,)
    float* outp = (float*)d_out;                 // (8,4,256,256)

    char* ws = (char*)d_ws;
    float*  zbuf = (float*)(ws);                       // 2 MB
    float*  Qb   = (float*)(ws + (2u << 20));          // 2 MB
    float2* At   = (float2*)(ws + (4u << 20));         // 4 MB
    float2* Ct0  = (float2*)(ws + (8u << 20));         // 4 MB
    float2* Ct1  = (float2*)(ws + (12u << 20));        // 4 MB
    if (ws_size < (16u << 20)) return;                 // need 16 MB scratch

    void* kargs[] = { (void*)&zeta, (void*)&Q0, (void*)&W1, (void*)&b1,
                      (void*)&W2, (void*)&b2, (void*)&outp, (void*)&zbuf,
                      (void*)&Qb, (void*)&At, (void*)&Ct0, (void*)&Ct1 };
    hipError_t err = hipLaunchCooperativeKernel((const void*)mega_kernel,
                                                dim3(768), dim3(256),
                                                kargs, 0, stream);
    if (err == hipSuccess) return;

    // Fallback: 48-dispatch path (round-3 validated)
    for (int step = 0; step < 16; ++step) {
        const float* zs = (step == 0) ? zeta : zbuf;
        step1_kernel<<<2304, 256, 0, stream>>>(zs, Q0, W1, b1, W2, b2, Qb, At);
        fftBC_kernel<<<512, 256, 0, stream>>>(At, Ct0, Ct1);
        float* op = ((step & 3) == 3) ? (outp + (size_t)(step >> 2) * NG * NG)
                                      : nullptr;
        fftD_kernel<<<1024, 256, 0, stream>>>(Ct0, Ct1, zs, Qb, zbuf, op);
    }
}

// Round 5
// 867.539 us; speedup vs baseline: 5.2525x; 5.2525x over previous
//
#include <hip/hip_runtime.h>

#define NG 256
#define PI2F 6.28318530717958647692f
// padded LDS complex index: pad 1 float2 per 16 to break bank aliasing
#define PIDX(i) ((i) + ((i) >> 4))
#define HT_CELL 36

__device__ __forceinline__ float2 f2add(float2 a, float2 b){ return make_float2(a.x+b.x, a.y+b.y); }
__device__ __forceinline__ float2 f2sub(float2 a, float2 b){ return make_float2(a.x-b.x, a.y-b.y); }
__device__ __forceinline__ float2 cmul(float2 a, float2 b){ return make_float2(a.x*b.x - a.y*b.y, a.x*b.y + a.y*b.x); }

// ---------------------------------------------------------------------------
// 256-pt radix-4 Stockham FFT, 64 threads per FFT unit (u = lane 0..63).
// Buffers a,b PIDX-padded (272 float2). tw[j]=exp(-2πi j/256). Result ends
// back in `a`. ALL threads of the block must call (internal barriers); `act`
// masks the work for idle units. Caller syncs after filling a/tw.
// (math validated rounds 2-4)
// ---------------------------------------------------------------------------
template<bool INV>
__device__ __forceinline__ void fft256_r4(float2* a, float2* b, const float2* tw,
                                          int u, bool act)
{
#pragma unroll
    for (int st = 0; st < 4; ++st) {
        if (act) {
            const int sl = 2 * st;
            const int q  = u & ((1 << sl) - 1);
            const int j1 = u - q;                 // p << sl  (twiddle index, <64)
            const float2 x0 = a[PIDX(u)];
            const float2 x1 = a[PIDX(u + 64)];
            const float2 x2 = a[PIDX(u + 128)];
            const float2 x3 = a[PIDX(u + 192)];
            float2 w1 = tw[j1];
            if (INV) w1.y = -w1.y;
            const float2 w2 = cmul(w1, w1);
            const float2 w3 = cmul(w1, w2);
            const float2 apc = f2add(x0, x2), amc = f2sub(x0, x2);
            const float2 bpd = f2add(x1, x3), bmd = f2sub(x1, x3);
            const float2 jb  = make_float2(-bmd.y, bmd.x);      // j*(b-d)
            const float2 t0  = f2add(apc, bpd);
            const float2 t2  = f2sub(apc, bpd);
            const float2 t1  = INV ? f2add(amc, jb) : f2sub(amc, jb);
            const float2 t3  = INV ? f2sub(amc, jb) : f2add(amc, jb);
            const int wb = q + (j1 << 2);         // q + 4*s*p
            const int ss = 1 << sl;
            b[PIDX(wb)]          = t0;
            b[PIDX(wb + ss)]     = cmul(w1, t1);
            b[PIDX(wb + 2 * ss)] = cmul(w2, t2);
            b[PIDX(wb + 3 * ss)] = cmul(w3, t3);
        }
        __syncthreads();
        float2* tmp = a; a = b; b = tmp;
    }
}

__device__ __forceinline__ void init_tw(float2* tw, int tid)
{
    if (tid < 256) {
        float s, c;
        __sincosf(-PI2F * (float)tid * (1.f / 256.f), &s, &c);
        tw[tid] = make_float2(c, s);
    }
}

// ---------------------------------------------------------------------------
// G kernel (row pass), 256 blocks x 512 threads; block = (batch b, band of 8
// rows y0..y0+7).   G_j = [ conv(z_{j-1}) -> Q (LDS only);
//                           D_{j-1}: inverse row-FFTs of Ct + update -> z_j;
//                           A: fwd row-FFT of z_j -> At (transposed) ]
// do_convd=0 (first dispatch): only A, zband loaded from global zin.
// do_a=0 (last dispatch): only conv+D.
// LDS pool layout (bytes):
//   tw    [0,2048)        Qlds [2048,10240)     zband [10240,18432)
//   zt    [18432,30912)   w1s  [30912,32064)    w2s   [32064,33216)
//   b1s   [33216,33344)   b2s  [33344,33360)
//   union [33360,82320): conv ht (48960) | fft bufs 16x272 f2 (34816)
// ---------------------------------------------------------------------------
#define G_POOL 82320

__global__ void __launch_bounds__(512)
g_kernel(const float* __restrict__ zin, float* __restrict__ zout,
         const float2* __restrict__ Ct0, const float2* __restrict__ Ct1,
         float2* __restrict__ At,
         const float* __restrict__ Q0, const float* __restrict__ W1,
         const float* __restrict__ b1, const float* __restrict__ W2,
         const float* __restrict__ b2, float* __restrict__ outp,
         int do_convd, int do_a)
{
    __shared__ __align__(16) char pool[G_POOL];
    float2* tw    = (float2*)pool;
    float*  Qlds  = (float*)(pool + 2048);
    float*  zband = (float*)(pool + 10240);
    float*  zt    = (float*)(pool + 18432);
    float4* w1s   = (float4*)(pool + 30912);
    float4* w2s   = (float4*)(pool + 32064);
    float*  b1s   = (float*)(pool + 33216);
    float*  b2s   = (float*)(pool + 33344);
    float*  ht    = (float*)(pool + 33360);
    float2* bufs  = (float2*)(pool + 33360);

    const int tid = threadIdx.x;
    const int b   = blockIdx.x >> 5;
    const int yg  = blockIdx.x & 31;
    const int y0  = yg * 8;

    init_tw(tw, tid);

    if (do_convd) {
        // ---- weights + z tile (rows y0-2..y0+9, cols -2..257, zero-padded)
        if (tid < 72) {
            w1s[tid] = ((const float4*)W1)[tid];
            w2s[tid] = ((const float4*)W2)[tid];
        }
        if (tid < 32) b1s[tid] = b1[tid];
        if (tid == 0) b2s[0] = b2[0];
        for (int i = tid; i < 12 * 260; i += 512) {
            const int r = i / 260, c = i - r * 260;
            const int gy = y0 - 2 + r, gx = c - 2;
            float v = 0.f;
            if ((unsigned)gy < 256u && (unsigned)gx < 256u)
                v = zin[(b * NG + gy) * NG + gx];
            zt[i] = v;
        }
        __syncthreads();

        // ---- conv (x-chunks of 32): Q = Q0 + 0.01*conv2(relu(conv1(z)))
        for (int c = 0; c < 8; ++c) {
            const int x0 = 32 * c;
            // conv1+ReLU: h rows y0-1..y0+8 (10), h cols x0-1..x0+32 (34)
            for (int i = tid; i < 2720; i += 512) {
                const int pos = i >> 3, cg = i & 7;
                const int hy = pos / 34, hx = pos - hy * 34;
                const int gr = y0 - 1 + hy;
                const int gc = x0 - 1 + hx;
                float4 acc = make_float4(0.f, 0.f, 0.f, 0.f);
                if ((unsigned)gr < 256u && (unsigned)gc < 256u) {
                    acc = make_float4(b1s[cg * 4], b1s[cg * 4 + 1],
                                      b1s[cg * 4 + 2], b1s[cg * 4 + 3]);
#pragma unroll
                    for (int dy = 0; dy < 3; dy++)
#pragma unroll
                        for (int dx = 0; dx < 3; dx++) {
                            const float zv = zt[(hy + dy) * 260 + (gc + 1 + dx)];
                            const float4 w = w1s[(dy * 3 + dx) * 8 + cg];
                            acc.x += w.x * zv; acc.y += w.y * zv;
                            acc.z += w.z * zv; acc.w += w.w * zv;
                        }
                    acc.x = fmaxf(acc.x, 0.f); acc.y = fmaxf(acc.y, 0.f);
                    acc.z = fmaxf(acc.z, 0.f); acc.w = fmaxf(acc.w, 0.f);
                }
                *((float4*)&ht[(hy * 34 + hx) * HT_CELL + cg * 4]) = acc;
            }
            __syncthreads();
            // conv2: 8 rows x 32 cols, one px per thread (tid<256)
            if (tid < 256) {
                const int oy = tid >> 5, ox = tid & 31;
                const int gor = y0 + oy, goc = x0 + ox;
                float qv = b2s[0];
#pragma unroll
                for (int dy = 0; dy < 3; dy++)
#pragma unroll
                    for (int dx = 0; dx < 3; dx++) {
                        const float* hc = &ht[((oy + dy) * 34 + (ox + dx)) * HT_CELL];
#pragma unroll
                        for (int cg = 0; cg < 8; cg++) {
                            const float4 hv = *((const float4*)&hc[cg * 4]);
                            const float4 w  = w2s[(dy * 3 + dx) * 8 + cg];
                            qv += w.x * hv.x + w.y * hv.y + w.z * hv.z + w.w * hv.w;
                        }
                    }
                Qlds[oy * NG + goc] = Q0[gor * NG + goc] + 0.01f * qv;
            }
            __syncthreads();
        }

        // ---- D: 16 inverse FFTs (8 rows x 2 fields), 8 units/round x 2
        const int ju = tid >> 6, u = tid & 63;
        for (int r = 0; r < 2; ++r) {
            const int idx8 = 8 * r + ju;
            const int rr = idx8 >> 1, f = idx8 & 1;
            float2* A = bufs + ju * 272;
            float2* B = bufs + (8 + ju) * 272;
            const float2* src = (f ? Ct1 : Ct0) + ((size_t)(b * NG + y0 + rr)) * NG;
#pragma unroll
            for (int r4 = 0; r4 < 4; ++r4) {
                const int x = u + 64 * r4;
                A[PIDX(x)] = src[x];
            }
            __syncthreads();
            fft256_r4<true>(A, B, tw, u, true);
            // update rows 4r..4r+3 (results are in units 2*lr / 2*lr+1)
            const float sc = 1.f / 256.f;
#pragma unroll
            for (int i0 = 0; i0 < 2; ++i0) {
                const int i  = tid + 512 * i0;       // 0..1023
                const int lr = i >> 8;               // 0..3
                const int x  = i & 255;
                const int row = 4 * r + lr;
                const float2 uvv = (bufs + (2 * lr) * 272)[PIDX(x)];
                const float2 gzz = (bufs + (2 * lr + 1) * 272)[PIDX(x)];
                const float uu = uvv.x * sc, vv = uvv.y * sc;
                const float zx = gzz.x * sc, zy = gzz.y * sc;
                const float z0v = zt[(row + 2) * 260 + (x + 2)];
                const float qv  = Qlds[row * NG + x];
                const float adv = uu * zx + vv * zy;
                const float zn = z0v + 0.01f * (-adv - 0.5f * vv - 0.05f * z0v + qv);
                zband[row * NG + x] = zn;
                zout[(b * NG + y0 + row) * NG + x] = zn;
                if (outp) outp[b * (4 * NG * NG) + (y0 + row) * NG + x] = zn;
            }
            __syncthreads();
        }
    } else {
        // first dispatch: zband direct from global input
        for (int i = tid; i < 8 * NG; i += 512)
            zband[i] = zin[(b * NG + y0) * NG + i];
        __syncthreads();
    }

    if (do_a) {
        // ---- A: fwd row-FFT of z_j band; 4 packed units (rows 2j,2j+1)
        const int ju = tid >> 6, u = tid & 63;
        const bool act = ju < 4;
        float2* A = bufs + ju * 272;
        float2* B = bufs + (8 + ju) * 272;
        if (act) {
            const int ra = 2 * ju;
#pragma unroll
            for (int r4 = 0; r4 < 4; ++r4) {
                const int x = u + 64 * r4;
                A[PIDX(x)] = make_float2(zband[ra * NG + x], zband[(ra + 1) * NG + x]);
            }
        }
        __syncthreads();
        fft256_r4<false>(A, B, tw, u, act);
        // Hermitian unpack + coalesced transposed write At[b][kx][y0..y0+7]
        if (tid < 256) {
            const int k  = tid;
            const int km = (256 - k) & 255;
            float2 outv[8];
#pragma unroll
            for (int jj = 0; jj < 4; ++jj) {
                const float2* Aj = bufs + jj * 272;
                const float2 Zk = Aj[PIDX(k)], Zm = Aj[PIDX(km)];
                outv[2 * jj] = make_float2(0.5f * (Zk.x + Zm.x), 0.5f * (Zk.y - Zm.y));
                const float dx = Zk.x - Zm.x, dy = Zk.y + Zm.y;
                outv[2 * jj + 1] = make_float2(0.5f * dy, -0.5f * dx);
            }
            float4* dst = (float4*)(At + ((size_t)(b * NG + k)) * NG + y0);
#pragma unroll
            for (int q4 = 0; q4 < 4; ++q4) dst[q4] = ((float4*)outv)[q4];
        }
    }
}

// ---------------------------------------------------------------------------
// BC (col pass): 4 kx-lines per block. fwd FFT along y, spectral multiplies
// (Hermitian-projection Nyquist masks), two packed inverse FFTs, coalesced
// transposed writes Ct[f][b][y][kx] scaled by 1/256. (validated r2-r4)
// ---------------------------------------------------------------------------
#define BC_POOL 28160

__global__ void __launch_bounds__(256)
fftBC_kernel(const float2* __restrict__ At,
             float2* __restrict__ Ct0, float2* __restrict__ Ct1)
{
    __shared__ __align__(16) char pool[BC_POOL];
    float2* bufs = (float2*)pool;   // A_j=j*272, B_j=(4+j)*272, C_j=(8+j)*272
    float2* tw   = bufs + 3264;
    const int bid = blockIdx.x;
    const int b  = bid >> 6;
    const int kg = bid & 63;
    const int tid = threadIdx.x;
    const int j = tid >> 6, u = tid & 63;
    float2* A = bufs + j * 272;
    float2* B = bufs + (4 + j) * 272;
    float2* C = bufs + (8 + j) * 272;

    init_tw(tw, tid);
    const int kxl = 4 * kg + j;
    const float2* src = At + ((size_t)(b * NG + kxl)) * NG;
#pragma unroll
    for (int r = 0; r < 4; ++r) {
        const int x = u + 64 * r;
        A[PIDX(x)] = src[x];
    }
    __syncthreads();
    fft256_r4<false>(A, B, tw, u, true);

    const float kxv = (kxl < 128) ? (float)kxl : (float)(kxl - 256);
    const float kxm = (kxl == 128) ? 0.f : kxv;
#pragma unroll
    for (int r = 0; r < 4; ++r) {
        const int ky = u + 64 * r;
        const float kyv = (ky < 128) ? (float)ky : (float)(ky - 256);
        const float kym = (ky == 128) ? 0.f : kyv;
        const float K2 = kxv * kxv + kyv * kyv;
        const float il = (K2 > 0.f) ? (-1.f / K2) : 0.f;
        const float2 Z = A[PIDX(ky)];
        const float ar = -kxm * il, ai = -kym * il;
        A[PIDX(ky)] = make_float2(ar * Z.x - ai * Z.y, ar * Z.y + ai * Z.x);
        C[PIDX(ky)] = make_float2(-kym * Z.x - kxm * Z.y, -kym * Z.y + kxm * Z.x);
    }
    __syncthreads();

    fft256_r4<true>(A, B, tw, u, true);
    {   // field0 (u + i v), thread tid = y
        const int y = tid;
        const float sc = 1.f / 256.f;
        float2 ov[4];
#pragma unroll
        for (int jj = 0; jj < 4; ++jj) {
            const float2 r0 = (bufs + jj * 272)[PIDX(y)];
            ov[jj] = make_float2(r0.x * sc, r0.y * sc);
        }
        float4* dst = (float4*)(Ct0 + ((size_t)(b * NG + y)) * NG + 4 * kg);
        dst[0] = ((float4*)ov)[0];
        dst[1] = ((float4*)ov)[1];
    }
    fft256_r4<true>(C, B, tw, u, true);
    {   // field1 (zx + i zy)
        const int y = tid;
        const float sc = 1.f / 256.f;
        float2 ov[4];
#pragma unroll
        for (int jj = 0; jj < 4; ++jj) {
            const float2 r1 = (bufs + (8 + jj) * 272)[PIDX(y)];
            ov[jj] = make_float2(r1.x * sc, r1.y * sc);
        }
        float4* dst = (float4*)(Ct1 + ((size_t)(b * NG + y)) * NG + 4 * kg);
        dst[0] = ((float4*)ov)[0];
        dst[1] = ((float4*)ov)[1];
    }
}

// ---------------------------------------------------------------------------
extern "C" void kernel_launch(void* const* d_in, const int* in_sizes, int n_in,
                              void* d_out, int out_size, void* d_ws, size_t ws_size,
                              hipStream_t stream)
{
    const float* zeta = (const float*)d_in[0];   // (8,256,256)
    const float* Q0   = (const float*)d_in[1];   // (256,256)
    const float* W1   = (const float*)d_in[2];   // (3,3,1,32)
    const float* b1   = (const float*)d_in[3];   // (32,)
    const float* W2   = (const float*)d_in[4];   // (3,3,32,1)
    const float* b2   = (const float*)d_in[5];   // (1,)
    float* outp = (float*)d_out;                 // (8,4,256,256)

    char* ws = (char*)d_ws;
    float*  z1  = (float*)(ws);                        // 2 MB  (z_odd)
    float*  z2  = (float*)(ws + (2u << 20));           // 2 MB  (z_even)
    float2* At  = (float2*)(ws + (4u << 20));          // 4 MB
    float2* Ct0 = (float2*)(ws + (8u << 20));          // 4 MB
    float2* Ct1 = (float2*)(ws + (12u << 20));         // 4 MB
    if (ws_size < (16u << 20)) return;                 // need 16 MB scratch

    // G_0: row-FFT of z_0 only
    g_kernel<<<256, 512, 0, stream>>>(zeta, z1, Ct0, Ct1, At,
                                      Q0, W1, b1, W2, b2, nullptr, 0, 1);
    fftBC_kernel<<<512, 256, 0, stream>>>(At, Ct0, Ct1);

    for (int j = 1; j <= 16; ++j) {
        const float* zin = (j == 1) ? zeta : ((j & 1) ? z2 : z1); // z_{j-1}
        float*       zo  = (j & 1) ? z1 : z2;                     // z_j
        float* op = (j % 4 == 0) ? (outp + (size_t)(j / 4 - 1) * NG * NG)
                                 : nullptr;
        g_kernel<<<256, 512, 0, stream>>>(zin, zo, Ct0, Ct1, At,
                                          Q0, W1, b1, W2, b2, op,
                                          1, (j < 16) ? 1 : 0);
        if (j < 16) fftBC_kernel<<<512, 256, 0, stream>>>(At, Ct0, Ct1);
    }
}

// Round 6
// 666.494 us; speedup vs baseline: 6.8369x; 1.3016x over previous
//
#include <hip/hip_runtime.h>

#define NG 256
#define PI2F 6.28318530717958647692f
// padded LDS complex index: pad 1 float2 per 16 to break bank aliasing
#define PIDX(i) ((i) + ((i) >> 4))
#define HT_CELL 36

__device__ __forceinline__ float2 f2add(float2 a, float2 b){ return make_float2(a.x+b.x, a.y+b.y); }
__device__ __forceinline__ float2 f2sub(float2 a, float2 b){ return make_float2(a.x-b.x, a.y-b.y); }
__device__ __forceinline__ float2 cmul(float2 a, float2 b){ return make_float2(a.x*b.x - a.y*b.y, a.x*b.y + a.y*b.x); }

// ---------------------------------------------------------------------------
// 256-pt radix-4 Stockham FFT, 64 threads per FFT unit (u = lane 0..63).
// Buffers a,b PIDX-padded (272 float2). tw[j]=exp(-2πi j/256). Result ends
// back in `a` (4 stages = even #swaps). ALL threads of the block must call
// (internal barriers); `act` masks work for idle units. Single call-site per
// code path => uniform barriers. (math validated rounds 2-5)
// ---------------------------------------------------------------------------
template<bool INV>
__device__ __forceinline__ void fft256_r4(float2* a, float2* b, const float2* tw,
                                          int u, bool act)
{
#pragma unroll
    for (int st = 0; st < 4; ++st) {
        if (act) {
            const int sl = 2 * st;
            const int q  = u & ((1 << sl) - 1);
            const int j1 = u - q;                 // p << sl  (twiddle index, <64)
            const float2 x0 = a[PIDX(u)];
            const float2 x1 = a[PIDX(u + 64)];
            const float2 x2 = a[PIDX(u + 128)];
            const float2 x3 = a[PIDX(u + 192)];
            float2 w1 = tw[j1];
            if (INV) w1.y = -w1.y;
            const float2 w2 = cmul(w1, w1);
            const float2 w3 = cmul(w1, w2);
            const float2 apc = f2add(x0, x2), amc = f2sub(x0, x2);
            const float2 bpd = f2add(x1, x3), bmd = f2sub(x1, x3);
            const float2 jb  = make_float2(-bmd.y, bmd.x);      // j*(b-d)
            const float2 t0  = f2add(apc, bpd);
            const float2 t2  = f2sub(apc, bpd);
            const float2 t1  = INV ? f2add(amc, jb) : f2sub(amc, jb);
            const float2 t3  = INV ? f2sub(amc, jb) : f2add(amc, jb);
            const int wb = q + (j1 << 2);         // q + 4*s*p
            const int ss = 1 << sl;
            b[PIDX(wb)]          = t0;
            b[PIDX(wb + ss)]     = cmul(w1, t1);
            b[PIDX(wb + 2 * ss)] = cmul(w2, t2);
            b[PIDX(wb + 3 * ss)] = cmul(w3, t3);
        }
        __syncthreads();
        float2* tmp = a; a = b; b = tmp;
    }
}

__device__ __forceinline__ void init_tw(float2* tw, int tid)
{
    if (tid < 256) {
        float s, c;
        __sincosf(-PI2F * (float)tid * (1.f / 256.f), &s, &c);
        tw[tid] = make_float2(c, s);
    }
}

// ---------------------------------------------------------------------------
// R kernel (row pass): 1024 blocks x 256 threads; block = (b, 2 rows y0,y0+1).
//   do_d: D = inverse row-FFT of Ct (4 units: 2 rows x 2 fields) + pointwise
//         update z_j = z_{j-1} + DT*(-adv - beta*v - r*z + Q)  (z in-place OK:
//         each element read+written by the same thread only)
//   do_a: A = packed fwd row-FFT of the two fresh rows (1 unit via LDS) +
//         Hermitian unpack -> At[b][kx][y0..y0+1] (16B lane writes)
// NOTE: zin/zout may ALIAS (in-place) -> no __restrict__ on them.
// ---------------------------------------------------------------------------
#define R_POOL 19456   // tw 2048 + bufs 8*272*8

__global__ void __launch_bounds__(256)
r_kernel(const float* zin, float* zout,
         const float2* __restrict__ Ct0, const float2* __restrict__ Ct1,
         float2* __restrict__ At, const float* __restrict__ Qb,
         float* __restrict__ outp, int do_d, int do_a)
{
    __shared__ __align__(16) char pool[R_POOL];
    float2* tw   = (float2*)pool;
    float2* bufs = (float2*)(pool + 2048);   // 8 buffers x 272
    const int tid = threadIdx.x;
    const int b   = blockIdx.x >> 7;
    const int y0  = (blockIdx.x & 127) * 2;
    const int j   = tid >> 6, u = tid & 63;

    init_tw(tw, tid);

    if (do_d) {
        // ---- D: unit j handles (row y0+(j>>1), field j&1)
        float2* A = bufs + j * 272;
        float2* B = bufs + (4 + j) * 272;
        const float2* src = ((j & 1) ? Ct1 : Ct0)
                          + ((size_t)(b * NG + y0 + (j >> 1))) * NG;
#pragma unroll
        for (int r4 = 0; r4 < 4; ++r4) {
            const int x = u + 64 * r4;
            A[PIDX(x)] = src[x];
        }
        __syncthreads();
        fft256_r4<true>(A, B, tw, u, true);

        // ---- update (thread tid = column x, rows 0..1)
        const float sc = 1.f / 256.f;
        float zn01[2];
#pragma unroll
        for (int r = 0; r < 2; ++r) {
            const float2 uvv = (bufs + (2 * r) * 272)[PIDX(tid)];
            const float2 gzz = (bufs + (2 * r + 1) * 272)[PIDX(tid)];
            const float uu = uvv.x * sc, vv = uvv.y * sc;
            const float zx = gzz.x * sc, zy = gzz.y * sc;
            const int idx = (b * NG + y0 + r) * NG + tid;
            const float z0v = zin[idx];
            const float qv  = Qb[idx];
            const float adv = uu * zx + vv * zy;
            const float zn = z0v + 0.01f * (-adv - 0.5f * vv - 0.05f * z0v + qv);
            zout[idx] = zn;
            if (outp) outp[b * (4 * NG * NG) + (y0 + r) * NG + tid] = zn;
            zn01[r] = zn;
        }
        __syncthreads();                      // all bufs reads done
        bufs[PIDX(tid)] = make_float2(zn01[0], zn01[1]);   // pack rows into A0
        __syncthreads();
    } else {
        // first dispatch: pack z0 rows directly from global
        bufs[PIDX(tid)] = make_float2(zin[(b * NG + y0) * NG + tid],
                                      zin[(b * NG + y0 + 1) * NG + tid]);
        __syncthreads();
    }

    if (do_a) {
        // ---- A: packed fwd FFT (unit 0 active; all threads call for barriers)
        fft256_r4<false>(bufs, bufs + 4 * 272, tw, u, j == 0);
        // Hermitian unpack; thread tid = kx
        const int k  = tid;
        const int km = (256 - k) & 255;
        const float2 Zk = bufs[PIDX(k)], Zm = bufs[PIDX(km)];
        const float dx = Zk.x - Zm.x, dy = Zk.y + Zm.y;
        const float4 ov = make_float4(0.5f * (Zk.x + Zm.x), 0.5f * (Zk.y - Zm.y),
                                      0.5f * dy, -0.5f * dx);
        *((float4*)(At + ((size_t)(b * NG + k)) * NG + y0)) = ov;
    }
}

// ---------------------------------------------------------------------------
// COL kernel: 2560 blocks x 512 threads.
//   blocks [0,2048): conv role — Q = Q0 + 0.01*conv2(relu(conv1(z))), 16x16
//     tile (validated r2-r5; 512-thr: conv2 px split across 2 threads + shfl)
//   blocks [2048,2560): BC role — fwd FFT along y (4 kx-lines, units 0-3),
//     spectral multiplies (Hermitian-projection Nyquist masks), BOTH packed
//     inverse FFTs in one round (8 units), coalesced writes Ct[f][b][y][kx]
//     scaled 1/256.
// ---------------------------------------------------------------------------
#define COL_POOL 50704

__global__ void __launch_bounds__(512)
col_kernel(const float2* __restrict__ At, float2* __restrict__ Ct0,
           float2* __restrict__ Ct1, const float* __restrict__ zsrc,
           const float* __restrict__ Q0, const float* __restrict__ W1,
           const float* __restrict__ b1, const float* __restrict__ W2,
           const float* __restrict__ b2, float* __restrict__ Qb)
{
    __shared__ __align__(16) char pool[COL_POOL];
    const int tid = threadIdx.x;

    if (blockIdx.x < 2048) {
        // ---------------- conv role ----------------
        float*  zt  = (float*)pool;                       // 1600
        float*  ht  = (float*)(pool + 1600);              // 46656
        float4* w1s = (float4*)(pool + 48256);            // 1152
        float4* w2s = (float4*)(pool + 49408);            // 1152
        float*  b1s = (float*)(pool + 50560);             // 128
        float*  b2s = (float*)(pool + 50688);             // 16
        const int b   = blockIdx.x >> 8;
        const int ty0 = ((blockIdx.x >> 4) & 15) * 16, tx0 = (blockIdx.x & 15) * 16;

        if (tid < 72) {
            w1s[tid] = ((const float4*)W1)[tid];
            w2s[tid] = ((const float4*)W2)[tid];
        }
        if (tid < 32) b1s[tid] = b1[tid];
        if (tid == 0) b2s[0] = b2[0];

        for (int i = tid; i < 400; i += 512) {
            const int ly = i / 20, lx = i - ly * 20;
            const int gy = ty0 + ly - 2, gx = tx0 + lx - 2;
            float v = 0.f;
            if ((unsigned)gy < 256u && (unsigned)gx < 256u)
                v = zsrc[(b * NG + gy) * NG + gx];
            zt[ly * 20 + lx] = v;
        }
        __syncthreads();

        // conv1 + ReLU over 18x18 halo region, 8 channel-groups of 4
        for (int i = tid; i < 324 * 8; i += 512) {
            const int pos = i >> 3, cg = i & 7;
            const int hy = pos / 18, hx = pos - hy * 18;
            const int gy = ty0 + hy - 1, gx = tx0 + hx - 1;
            float4 acc = make_float4(0.f, 0.f, 0.f, 0.f);
            if ((unsigned)gy < 256u && (unsigned)gx < 256u) {
                acc = make_float4(b1s[cg * 4], b1s[cg * 4 + 1],
                                  b1s[cg * 4 + 2], b1s[cg * 4 + 3]);
#pragma unroll
                for (int dy = 0; dy < 3; dy++)
#pragma unroll
                    for (int dx = 0; dx < 3; dx++) {
                        const float zv = zt[(hy + dy) * 20 + hx + dx];
                        const float4 w = w1s[(dy * 3 + dx) * 8 + cg];
                        acc.x += w.x * zv; acc.y += w.y * zv;
                        acc.z += w.z * zv; acc.w += w.w * zv;
                    }
                acc.x = fmaxf(acc.x, 0.f); acc.y = fmaxf(acc.y, 0.f);
                acc.z = fmaxf(acc.z, 0.f); acc.w = fmaxf(acc.w, 0.f);
            }
            *((float4*)&ht[pos * HT_CELL + cg * 4]) = acc;
        }
        __syncthreads();

        // conv2: px = tid>>1; channel-halves split across thread pairs + shfl
        const int px = tid >> 1, half = tid & 1;
        const int oy = px >> 4, ox = px & 15;
        float qv = half ? 0.f : b2s[0];
#pragma unroll
        for (int dy = 0; dy < 3; dy++)
#pragma unroll
            for (int dx = 0; dx < 3; dx++) {
                const float* hc = &ht[((oy + dy) * 18 + (ox + dx)) * HT_CELL + half * 16];
#pragma unroll
                for (int cg2 = 0; cg2 < 4; cg2++) {
                    const float4 hv = *((const float4*)(hc + cg2 * 4));
                    const float4 w  = w2s[(dy * 3 + dx) * 8 + half * 4 + cg2];
                    qv += w.x * hv.x + w.y * hv.y + w.z * hv.z + w.w * hv.w;
                }
            }
        qv += __shfl_xor(qv, 1);
        if (!half) {
            const int gy = ty0 + oy, gx = tx0 + ox;
            Qb[(b * NG + gy) * NG + gx] = Q0[gy * NG + gx] + 0.01f * qv;
        }
    } else {
        // ---------------- BC role (8 FFT units) ----------------
        float2* tw   = (float2*)pool;                 // 2048
        float2* bufs = (float2*)(pool + 2048);        // 16 x 272 float2
        const int bid = blockIdx.x - 2048;            // 0..511
        const int b  = bid >> 6;
        const int kg = bid & 63;
        const int j8 = tid >> 6, u = tid & 63;

        init_tw(tw, tid);
        // load 4 kx-lines (units 0-3)
        if (j8 < 4) {
            const int kxl = 4 * kg + j8;
            float2* A = bufs + j8 * 272;
            const float2* src = At + ((size_t)(b * NG + kxl)) * NG;
#pragma unroll
            for (int r = 0; r < 4; ++r) {
                const int x = u + 64 * r;
                A[PIDX(x)] = src[x];
            }
        }
        __syncthreads();
        // fwd FFT along y (units 0-3)
        fft256_r4<false>(bufs + j8 * 272, bufs + (4 + (j8 & 3)) * 272, tw, u, j8 < 4);

        // spectral multiplies (validated mapping, threads 0-255)
        if (tid < 256) {
            const int jl = tid >> 6;                  // line 0..3
            const int kxl = 4 * kg + jl;
            float2* A = bufs + jl * 272;
            float2* C = bufs + (8 + jl) * 272;
            const float kxv = (kxl < 128) ? (float)kxl : (float)(kxl - 256);
            const float kxm = (kxl == 128) ? 0.f : kxv;
#pragma unroll
            for (int r = 0; r < 4; ++r) {
                const int ky = u + 64 * r;
                const float kyv = (ky < 128) ? (float)ky : (float)(ky - 256);
                const float kym = (ky == 128) ? 0.f : kyv;
                const float K2 = kxv * kxv + kyv * kyv;
                const float il = (K2 > 0.f) ? (-1.f / K2) : 0.f;
                const float2 Z = A[PIDX(ky)];
                const float ar = -kxm * il, ai = -kym * il;
                A[PIDX(ky)] = make_float2(ar * Z.x - ai * Z.y, ar * Z.y + ai * Z.x);
                C[PIDX(ky)] = make_float2(-kym * Z.x - kxm * Z.y, -kym * Z.y + kxm * Z.x);
            }
        }
        __syncthreads();

        // BOTH inverse FFTs in one round: units 0-3 field0 (A), 4-7 field1 (C)
        float2* ia = (j8 < 4) ? bufs + j8 * 272 : bufs + (8 + (j8 - 4)) * 272;
        float2* ib = (j8 < 4) ? bufs + (4 + j8) * 272 : bufs + (12 + (j8 - 4)) * 272;
        fft256_r4<true>(ia, ib, tw, u, true);

        // coalesced transposed writes (x 1/256): tid<256 field0, else field1
        const float sc = 1.f / 256.f;
        const int y = tid & 255;
        float2 ov[4];
        if (tid < 256) {
#pragma unroll
            for (int jj = 0; jj < 4; ++jj) {
                const float2 r0 = (bufs + jj * 272)[PIDX(y)];
                ov[jj] = make_float2(r0.x * sc, r0.y * sc);
            }
            float4* dst = (float4*)(Ct0 + ((size_t)(b * NG + y)) * NG + 4 * kg);
            dst[0] = ((float4*)ov)[0];
            dst[1] = ((float4*)ov)[1];
        } else {
#pragma unroll
            for (int jj = 0; jj < 4; ++jj) {
                const float2 r1 = (bufs + (8 + jj) * 272)[PIDX(y)];
                ov[jj] = make_float2(r1.x * sc, r1.y * sc);
            }
            float4* dst = (float4*)(Ct1 + ((size_t)(b * NG + y)) * NG + 4 * kg);
            dst[0] = ((float4*)ov)[0];
            dst[1] = ((float4*)ov)[1];
        }
    }
}

// ---------------------------------------------------------------------------
extern "C" void kernel_launch(void* const* d_in, const int* in_sizes, int n_in,
                              void* d_out, int out_size, void* d_ws, size_t ws_size,
                              hipStream_t stream)
{
    const float* zeta = (const float*)d_in[0];   // (8,256,256)
    const float* Q0   = (const float*)d_in[1];   // (256,256)
    const float* W1   = (const float*)d_in[2];   // (3,3,1,32)
    const float* b1   = (const float*)d_in[3];   // (32,)
    const float* W2   = (const float*)d_in[4];   // (3,3,32,1)
    const float* b2   = (const float*)d_in[5];   // (1,)
    float* outp = (float*)d_out;                 // (8,4,256,256)

    char* ws = (char*)d_ws;
    float*  zws = (float*)(ws);                        // 2 MB (z, in-place)
    float*  Qb  = (float*)(ws + (2u << 20));           // 2 MB
    float2* At  = (float2*)(ws + (4u << 20));          // 4 MB
    float2* Ct0 = (float2*)(ws + (8u << 20));          // 4 MB
    float2* Ct1 = (float2*)(ws + (12u << 20));         // 4 MB
    if (ws_size < (16u << 20)) return;                 // need 16 MB scratch

    // R0: row-FFT of z0 only
    r_kernel<<<1024, 256, 0, stream>>>(zeta, zws, Ct0, Ct1, At, Qb,
                                       nullptr, 0, 1);
    for (int j = 1; j <= 16; ++j) {
        const float* zp = (j == 1) ? zeta : zws;       // z_{j-1}
        // col_j: BC(At) -> Ct ; conv(z_{j-1}) -> Qb
        col_kernel<<<2560, 512, 0, stream>>>(At, Ct0, Ct1, zp,
                                             Q0, W1, b1, W2, b2, Qb);
        // R_j: D(Ct, z_{j-1}, Qb) -> z_j (in-place for j>=2), + A(z_j)
        float* op = (j % 4 == 0) ? (outp + (size_t)(j / 4 - 1) * NG * NG)
                                 : nullptr;
        r_kernel<<<1024, 256, 0, stream>>>(zp, zws, Ct0, Ct1, At, Qb,
                                           op, 1, (j < 16) ? 1 : 0);
    }
}